// Round 14
// baseline (682.566 us; speedup 1.0000x reference)
//
#include <hip/hip_runtime.h>

typedef __attribute__((ext_vector_type(8))) short bf16x8;
typedef __attribute__((ext_vector_type(4))) float f32x4;
typedef __attribute__((ext_vector_type(4))) unsigned int u32x4;
typedef __attribute__((ext_vector_type(2))) unsigned int u32x2;

#define NTOK 4096
#define CHD 256
// (1/sqrt(256)) * log2(e) folded into wq/bq so softmax uses exp2 directly
#define QSCALE 0.09016844005556022f
#define KB 32
#define NIT 32            // 1024 keys per block / KB
#define RESCALE_THR 8.0f

typedef unsigned int __attribute__((address_space(1))) gu32;
typedef unsigned int __attribute__((address_space(3))) lu32;
#define GLOAD(g, s) __builtin_amdgcn_global_load_lds((const gu32*)(const void*)(g), (lu32*)(void*)(s), 16, 0, 0)

__device__ __forceinline__ unsigned short f2bf(float x) {
    unsigned int u = __builtin_bit_cast(unsigned int, x);
    return (unsigned short)((u + 0x7FFFu + ((u >> 16) & 1u)) >> 16);
}
__device__ __forceinline__ float bf2f(unsigned short u) {
    return __builtin_bit_cast(float, (unsigned int)u << 16);
}
__device__ __forceinline__ f32x4 mfma16(bf16x8 a, bf16x8 b, f32x4 c) {
    return __builtin_amdgcn_mfma_f32_16x16x32_bf16(a, b, c, 0, 0, 0);
}
// all-reduce over the lane-quad {l, l^16, l^32, l^48} (proven r5-r12)
__device__ __forceinline__ float xmax32(float x) {
    x = fmaxf(x, __shfl_xor(x, 16));
    x = fmaxf(x, __shfl_xor(x, 32));
    return x;
}
__device__ __forceinline__ float xsum32(float x) {    // epilogue-only
    x += __shfl_xor(x, 16);
    x += __shfl_xor(x, 32);
    return x;
}
__device__ __forceinline__ unsigned int cvtpk(float lo, float hi) {
    unsigned int r;
    asm("v_cvt_pk_bf16_f32 %0, %1, %2" : "=v"(r) : "v"(lo), "v"(hi));
    return r;
}

// ---------------- kernel 1: weights fp32 -> bf16 (wq scaled) ----------------
__global__ __launch_bounds__(256) void wconv_kernel(
    const float* __restrict__ wq, const float* __restrict__ wk,
    const float* __restrict__ wv, unsigned short* __restrict__ wbf)
{
    int idx = blockIdx.x * 256 + threadIdx.x;     // 3*65536 total
    int z = idx >> 16;
    const float* src = (z == 0) ? wq : (z == 1) ? wk : wv;
    float s = (z == 0) ? QSCALE : 1.0f;
    wbf[idx] = f2bf(src[idx & 65535] * s);
}

// ---------------- kernel 2: fused 1x1-conv projection -----------------------
__global__ __launch_bounds__(256) void proj_kernel(
    const float* __restrict__ xq, const float* __restrict__ xk, const float* __restrict__ xv,
    const float* __restrict__ bq, const float* __restrict__ bk, const float* __restrict__ bv,
    const unsigned short* __restrict__ wbf,
    unsigned short* __restrict__ Qo, unsigned short* __restrict__ Ko,
    unsigned short* __restrict__ VTo)
{
    __shared__ __align__(16) unsigned short alds[64 * 264];
    __shared__ __align__(16) unsigned char wlds[16384];
    const int z = blockIdx.y;
    const int b = blockIdx.x >> 6;
    const int n0 = (blockIdx.x & 63) << 6;
    const float* x    = (z == 0) ? xq : (z == 1) ? xk : xv;
    const float* bias = (z == 0) ? bq : (z == 1) ? bk : bv;
    const unsigned short* w = wbf + z * 65536;
    const int t = threadIdx.x;
    const int wv_ = t >> 6, l = t & 63, lr = l & 15, lg = l >> 4;

    #pragma unroll
    for (int it = 0; it < 16; ++it) {
        int idx = it * 256 + t;
        int c = idx >> 4, j4 = idx & 15;
        f32x4 v = *(const f32x4*)(x + (size_t)(b * CHD + c) * NTOK + n0 + j4 * 4);
        #pragma unroll
        for (int i = 0; i < 4; ++i)
            alds[(j4 * 4 + i) * 264 + c] = f2bf(v[i]);
    }
    __syncthreads();

    bf16x8 af[8];
    #pragma unroll
    for (int kk = 0; kk < 8; ++kk)
        af[kk] = *(const bf16x8*)&alds[(wv_ * 16 + lr) * 264 + kk * 32 + lg * 8];

    const float bsc = (z == 0) ? QSCALE : 1.0f;

    for (int dg = 0; dg < 8; ++dg) {
        __syncthreads();
        #pragma unroll
        for (int it = 0; it < 4; ++it) {
            int idx = it * 256 + t;
            int dr = idx >> 5, c16 = idx & 31;
            u32x4 vv = *(const u32x4*)(w + (size_t)(dg * 32 + dr) * CHD + c16 * 8);
            *(u32x4*)(wlds + ((dr * 512 + c16 * 16) ^ ((dr & 7) << 4))) = vv;
        }
        __syncthreads();
        #pragma unroll
        for (int dbi = 0; dbi < 2; ++dbi) {
            int dr = dbi * 16 + lr;
            int d = dg * 32 + dr;
            float bias_v = bias[d] * bsc;
            f32x4 acc = {bias_v, bias_v, bias_v, bias_v};
            #pragma unroll
            for (int kk = 0; kk < 8; ++kk) {
                bf16x8 bf = *(const bf16x8*)(wlds + ((dr * 512 + kk * 64 + lg * 16) ^ ((dr & 7) << 4)));
                acc = mfma16(af[kk], bf, acc);
            }
            if (z < 2) {
                unsigned short* o = (z == 0) ? Qo : Ko;
                #pragma unroll
                for (int r = 0; r < 4; ++r) {
                    int n = n0 + wv_ * 16 + lg * 4 + r;
                    o[(size_t)(b * NTOK + n) * CHD + d] = f2bf(acc[r]);
                }
            } else {
                int n = n0 + wv_ * 16 + lg * 4;
                u32x2 pk;
                pk[0] = (unsigned)f2bf(acc[0]) | ((unsigned)f2bf(acc[1]) << 16);
                pk[1] = (unsigned)f2bf(acc[2]) | ((unsigned)f2bf(acc[3]) << 16);
                *(u32x2*)(VTo + (size_t)(b * CHD + d) * NTOK + n) = pk;
            }
        }
    }
}

// ---------------- kernel 3: flash attention (KV-split x4, 256q/block) -------
// r14: phase-decoupled pipeline WITHOUT the r13 register blowup. Per iter kt:
//   barrier -> stage{K(kt+3),V(kt+2)} -> PV(kt) [uses pb from last iter]
//   and QK^T(kt+1) [independent MFMA/LDS streams, interleavable]
//   -> softmax(kt+1) -> pb.
// Only ONE s-array + pb(8) live across the barrier (r13 kept two s-arrays and
// spilled: FETCH 17.5->23.4MB). Online-softmax order stays exact: o-rescale
// for tile kt+1 happens after PV(kt) accumulated.
// Ring-4 K bufs (64KB) + ring-4 V bufs (64KB). Stage indices CLAMPED to
// NIT-1 so every iter issues exactly 4 loads -> uniform vmcnt(4) (completes
// the group issued 2 iters ago: exactly K(kt+1),V(kt)). Clamped restages
// rewrite identical bytes (benign). Reuse safety (single barrier + own-lgkm
// drain, as r9): staged kbuf/vbuf last read 2 barriers ago.
// grid 256 (1 block/CU), block 512 (8 waves, 32 q-rows), waves_per_eu(2,2)
// pins 256 regs/wave (128 arch + 128 acc).
__global__ __attribute__((amdgpu_waves_per_eu(2, 2))) __launch_bounds__(512)
void attn_kernel(
    const unsigned short* __restrict__ Qp,
    const unsigned short* __restrict__ Kp,
    const unsigned short* __restrict__ VTp,
    unsigned short* __restrict__ Opart,      // (B,4,C,N) unnormalized bf16
    float* __restrict__ Mpart, float* __restrict__ Lpart)  // (B,4,N)
{
    __shared__ __align__(16) char smem[131072];
    const int bid = blockIdx.x;
    const int g = bid & 7, b = g >> 1, hf = g & 1;
    const int j = bid >> 3;
    const int q2 = j >> 4;
    const int n0 = (j & 15) * 256;
    const int part = hf * 2 + q2;
    const int kvbase = hf * 2048 + q2 * 1024;
    const int t = threadIdx.x;
    const int w = t >> 6, l = t & 63, lr = l & 15, lg = l >> 4;

    const char* Kby = (const char*)(Kp + (size_t)b * NTOK * CHD);
    const char* Vby = (const char*)(VTp + (size_t)b * CHD * NTOK);
    const unsigned short* Qb = Qp + (size_t)b * NTOK * CHD;

    // Q fragments: wave owns rows [n0 + w*32, +32)
    bf16x8 qf[2][8];
    #pragma unroll
    for (int nb = 0; nb < 2; ++nb)
        #pragma unroll
        for (int kk = 0; kk < 8; ++kk)
            qf[nb][kk] = *(const bf16x8*)(Qb + (size_t)(n0 + w * 32 + nb * 16 + lr) * CHD + kk * 32 + lg * 8);
    asm volatile("" ::: "memory");

    // stage K tile jt -> kbuf[jt&3] (2 GLOADs/wave)
    auto stageK = [&](int jt) {
        const char* ks = Kby + (size_t)(kvbase + jt * KB) * 512;
        char* kd = smem + (jt & 3) * 16384 + w * 2048;
        #pragma unroll
        for (int jj = 0; jj < 2; ++jj) {
            int p = w * 2048 + jj * 1024 + l * 16;
            int i = p >> 9, c = p & 511;
            int pi = ((i >> 2) & 3) * 8 + ((i >> 4) & 1) * 4 + (i & 3);  // row perm
            GLOAD(ks + pi * 512 + (c ^ ((i & 7) << 4)), kd + jj * 1024);
        }
    };
    // stage V tile jt -> vbuf[jt&3] (2 GLOADs/wave)
    auto stageV = [&](int jt) {
        const char* vs = Vby + (size_t)(kvbase + jt * KB) * 2;
        char* vd = smem + 65536 + (jt & 3) * 16384 + w * 2048;
        #pragma unroll
        for (int jj = 0; jj < 2; ++jj) {
            int p = w * 2048 + jj * 1024 + l * 16;
            GLOAD(vs + (p >> 6) * 8192 + (p & 63), vd + jj * 1024);  // V row d=p>>6
        }
    };

    // QK^T from kbuf: s[nb][cb] = S[k=cb*16+lg*4+r][q=nb*16+lr]
    auto qkcompute = [&](const char* kB, f32x4 (&s)[2][2]) {
        #pragma unroll
        for (int nb = 0; nb < 2; ++nb)
            #pragma unroll
            for (int cb = 0; cb < 2; ++cb)
                s[nb][cb] = (f32x4){0.f, 0.f, 0.f, 0.f};
        #pragma unroll
        for (int kk = 0; kk < 8; ++kk) {
            #pragma unroll
            for (int cb = 0; cb < 2; ++cb) {
                int row = cb * 16 + lr;
                bf16x8 kf = *(const bf16x8*)(kB + row * 512 + ((kk * 64 + lg * 16) ^ ((row & 7) << 4)));
                s[0][cb] = mfma16(kf, qf[0][kk], s[0][cb]);
                s[1][cb] = mfma16(kf, qf[1][kk], s[1][cb]);
            }
        }
    };

    f32x4 o[2][16];
    #pragma unroll
    for (int nb = 0; nb < 2; ++nb)
        #pragma unroll
        for (int db = 0; db < 16; ++db)
            o[nb][db] = (f32x4){0.f, 0.f, 0.f, 0.f};
    float mrow[2] = {-1e30f, -1e30f};
    float lpart[2] = {0.f, 0.f};      // per-lane partial; summed at epilogue

    f32x4 scur[2][2];
    bf16x8 pb[2];

    // softmax of scur (tile held in scur) -> pb; updates mrow/lpart and
    // rescales o under defer-max THR
    auto softmax = [&]() {
        float pm[2];
        #pragma unroll
        for (int nb = 0; nb < 2; ++nb) {
            float t8 = fmaxf(fmaxf(fmaxf(scur[nb][0][0], scur[nb][0][1]), fmaxf(scur[nb][0][2], scur[nb][0][3])),
                             fmaxf(fmaxf(scur[nb][1][0], scur[nb][1][1]), fmaxf(scur[nb][1][2], scur[nb][1][3])));
            pm[nb] = xmax32(t8);
        }
        bool grow = (pm[0] > mrow[0] + RESCALE_THR) || (pm[1] > mrow[1] + RESCALE_THR);
        if (__any((int)grow)) {
            #pragma unroll
            for (int nb = 0; nb < 2; ++nb) {
                float mn = fmaxf(mrow[nb], pm[nb]);
                float resc = __builtin_amdgcn_exp2f(mrow[nb] - mn);
                mrow[nb] = mn;
                lpart[nb] *= resc;
                f32x4 r4;                               // resc for q = lg*4 + r
                #pragma unroll
                for (int r = 0; r < 4; ++r)
                    r4[r] = __shfl(resc, lg * 4 + r);
                #pragma unroll
                for (int db = 0; db < 16; ++db)
                    o[nb][db] *= r4;
            }
        }
        #pragma unroll
        for (int nb = 0; nb < 2; ++nb) {
            float ps = 0.f;
            #pragma unroll
            for (int cb = 0; cb < 2; ++cb)
                #pragma unroll
                for (int r = 0; r < 4; ++r) {
                    float p = __builtin_amdgcn_exp2f(scur[nb][cb][r] - mrow[nb]);
                    scur[nb][cb][r] = p;
                    ps += p;
                }
            lpart[nb] += ps;
            u32x4 pw;                                   // -> PV A-frag (pi order)
            pw[0] = cvtpk(scur[nb][0][0], scur[nb][0][1]);
            pw[1] = cvtpk(scur[nb][0][2], scur[nb][0][3]);
            pw[2] = cvtpk(scur[nb][1][0], scur[nb][1][1]);
            pw[3] = cvtpk(scur[nb][1][2], scur[nb][1][3]);
            pb[nb] = __builtin_bit_cast(bf16x8, pw);
        }
    };

    // prologue: K0,K1,V0 resident; K2,V1 in flight; softmax(tile 0) -> pb
    stageK(0); stageK(1); stageV(0);
    stageK(2); stageV(1);
    asm volatile("s_waitcnt vmcnt(4)" ::: "memory");
    __builtin_amdgcn_s_barrier();
    qkcompute(smem, scur);
    softmax();

    #pragma unroll 1
    for (int kt = 0; kt < NIT; ++kt) {
        // need V(kt), K(kt+1) resident: completed by vmcnt(4) (the group
        // issued 2 iters back); drain own LDS reads, then block-sync.
        asm volatile("s_waitcnt lgkmcnt(0) vmcnt(4)" ::: "memory");
        __builtin_amdgcn_s_barrier();
        __builtin_amdgcn_sched_barrier(0);
        {   // clamped staging: always 4 loads/iter
            int jk = kt + 3 < NIT ? kt + 3 : NIT - 1;
            int jv = kt + 2 < NIT ? kt + 2 : NIT - 1;
            stageK(jk);
            stageV(jv);
        }

        // ---- PV(kt) [pb x V] and QK^T(kt+1): independent streams ----
        __builtin_amdgcn_s_setprio(1);
        const char* vB = smem + 65536 + (kt & 3) * 16384;
        #pragma unroll
        for (int db = 0; db < 16; ++db) {
            bf16x8 vf = *(const bf16x8*)(vB + (db * 16 + lr) * 64 + lg * 16);
            o[0][db] = mfma16(pb[0], vf, o[0][db]);
            o[1][db] = mfma16(pb[1], vf, o[1][db]);
        }
        if (kt + 1 < NIT)
            qkcompute(smem + ((kt + 1) & 3) * 16384, scur);
        __builtin_amdgcn_s_setprio(0);

        // ---- softmax(kt+1) -> pb for next iter ----
        if (kt + 1 < NIT)
            softmax();
    }

    // ---- epilogue: one cross-lane l-sum, then write the 32-row partial ----
    float lrow[2];
    #pragma unroll
    for (int nb = 0; nb < 2; ++nb)
        lrow[nb] = xsum32(lpart[nb]);

    unsigned short* Ob = Opart + (size_t)(b * 4 + part) * CHD * NTOK;
    #pragma unroll
    for (int nb = 0; nb < 2; ++nb)
        #pragma unroll
        for (int db = 0; db < 16; ++db) {
            int d = db * 16 + lr;
            int n = n0 + w * 32 + nb * 16 + lg * 4;
            u32x2 pk;
            pk[0] = (unsigned)f2bf(o[nb][db][0]) | ((unsigned)f2bf(o[nb][db][1]) << 16);
            pk[1] = (unsigned)f2bf(o[nb][db][2]) | ((unsigned)f2bf(o[nb][db][3]) << 16);
            *(u32x2*)(Ob + (size_t)d * NTOK + n) = pk;
        }
    if (lg == 0) {    // lanes 0..15 hold m/l for q = lr
        #pragma unroll
        for (int nb = 0; nb < 2; ++nb) {
            int n = n0 + w * 32 + nb * 16 + lr;
            Mpart[(size_t)(b * 4 + part) * NTOK + n] = mrow[nb];
            Lpart[(size_t)(b * 4 + part) * NTOK + n] = lrow[nb];
        }
    }
}

// ---------------- kernel 4: merge the four KV-quarter partials --------------
__global__ __launch_bounds__(256) void merge_kernel(
    const unsigned short* __restrict__ Opart,
    const float* __restrict__ Mpart, const float* __restrict__ Lpart,
    float* __restrict__ out)
{
    int tid = blockIdx.x * 256 + threadIdx.x;
    int n = (tid & 1023) * 4;
    int c = (tid >> 10) & 255;
    int b = tid >> 18;
    u32x2 ov[4]; f32x4 mv[4], lv[4];
    #pragma unroll
    for (int p = 0; p < 4; ++p) {
        ov[p] = *(const u32x2*)(Opart + (size_t)(b * 4 + p) * CHD * NTOK + (size_t)c * NTOK + n);
        mv[p] = *(const f32x4*)(Mpart + (size_t)(b * 4 + p) * NTOK + n);
        lv[p] = *(const f32x4*)(Lpart + (size_t)(b * 4 + p) * NTOK + n);
    }
    f32x4 res;
    #pragma unroll
    for (int r = 0; r < 4; ++r) {
        float mm = fmaxf(fmaxf(mv[0][r], mv[1][r]), fmaxf(mv[2][r], mv[3][r]));
        float num = 0.f, den = 0.f;
        #pragma unroll
        for (int p = 0; p < 4; ++p) {
            float sc = __builtin_amdgcn_exp2f(mv[p][r] - mm);
            num += bf2f((unsigned short)(ov[p][r >> 1] >> ((r & 1) * 16))) * sc;
            den += lv[p][r] * sc;
        }
        res[r] = num / den;
    }
    *(f32x4*)(out + (size_t)b * CHD * NTOK + (size_t)c * NTOK + n) = res;
}

// ---------------------------------------------------------------------------
extern "C" void kernel_launch(void* const* d_in, const int* in_sizes, int n_in,
                              void* d_out, int out_size, void* d_ws, size_t ws_size,
                              hipStream_t stream) {
    const float* xq = (const float*)d_in[0];
    const float* xk = (const float*)d_in[1];
    const float* xv = (const float*)d_in[2];
    const float* wq = (const float*)d_in[3];
    const float* bq = (const float*)d_in[4];
    const float* wk = (const float*)d_in[5];
    const float* bk = (const float*)d_in[6];
    const float* wv = (const float*)d_in[7];
    const float* bv = (const float*)d_in[8];

    char* ws = (char*)d_ws;
    unsigned short* wbf = (unsigned short*)ws;                       // 384 KB
    unsigned short* Qp  = (unsigned short*)(ws + 393216);            // 8 MB
    unsigned short* Kp  = (unsigned short*)(ws + 8781824);           // 8 MB
    unsigned short* VTp = (unsigned short*)(ws + 17170432);          // 8 MB
    unsigned short* Op  = (unsigned short*)(ws + 25559040);          // 32 MB
    float* Mp = (float*)(ws + 59113472);                             // 256 KB
    float* Lp = (float*)(ws + 59375616);                             // 256 KB

    hipLaunchKernelGGL(wconv_kernel, dim3(768), dim3(256), 0, stream, wq, wk, wv, wbf);
    hipLaunchKernelGGL(proj_kernel, dim3(256, 3), dim3(256), 0, stream,
                       xq, xk, xv, bq, bk, bv, wbf, Qp, Kp, VTp);
    hipLaunchKernelGGL(attn_kernel, dim3(256), dim3(512), 0, stream, Qp, Kp, VTp, Op, Mp, Lp);
    hipLaunchKernelGGL(merge_kernel, dim3(4096), dim3(256), 0, stream, Op, Mp, Lp, (float*)d_out);
}

// Round 15
// 126.124 us; speedup vs baseline: 5.4119x; 5.4119x over previous
//
#include <hip/hip_runtime.h>

typedef __attribute__((ext_vector_type(8))) short bf16x8;
typedef __attribute__((ext_vector_type(4))) float f32x4;
typedef __attribute__((ext_vector_type(4))) unsigned int u32x4;
typedef __attribute__((ext_vector_type(2))) unsigned int u32x2;

#define NTOK 4096
#define CHD 256
// (1/sqrt(256)) * log2(e) folded into wq/bq so softmax uses exp2 directly
#define QSCALE 0.09016844005556022f
#define KB 32
#define NIT 32            // 1024 keys per block / KB
#define RESCALE_THR 8.0f

typedef unsigned int __attribute__((address_space(1))) gu32;
typedef unsigned int __attribute__((address_space(3))) lu32;
#define GLOAD(g, s) __builtin_amdgcn_global_load_lds((const gu32*)(const void*)(g), (lu32*)(void*)(s), 16, 0, 0)

__device__ __forceinline__ unsigned short f2bf(float x) {
    unsigned int u = __builtin_bit_cast(unsigned int, x);
    return (unsigned short)((u + 0x7FFFu + ((u >> 16) & 1u)) >> 16);
}
__device__ __forceinline__ float bf2f(unsigned short u) {
    return __builtin_bit_cast(float, (unsigned int)u << 16);
}
__device__ __forceinline__ f32x4 mfma16(bf16x8 a, bf16x8 b, f32x4 c) {
    return __builtin_amdgcn_mfma_f32_16x16x32_bf16(a, b, c, 0, 0, 0);
}
// all-reduce over the lane-quad {l, l^16, l^32, l^48} (proven r5-r12)
__device__ __forceinline__ float xmax32(float x) {
    x = fmaxf(x, __shfl_xor(x, 16));
    x = fmaxf(x, __shfl_xor(x, 32));
    return x;
}
__device__ __forceinline__ float xsum32(float x) {    // epilogue-only
    x += __shfl_xor(x, 16);
    x += __shfl_xor(x, 32);
    return x;
}
__device__ __forceinline__ unsigned int cvtpk(float lo, float hi) {
    unsigned int r;
    asm("v_cvt_pk_bf16_f32 %0, %1, %2" : "=v"(r) : "v"(lo), "v"(hi));
    return r;
}

// ---------------- kernel 1: weights fp32 -> bf16 (wq scaled) ----------------
__global__ __launch_bounds__(256) void wconv_kernel(
    const float* __restrict__ wq, const float* __restrict__ wk,
    const float* __restrict__ wv, unsigned short* __restrict__ wbf)
{
    int idx = blockIdx.x * 256 + threadIdx.x;     // 3*65536 total
    int z = idx >> 16;
    const float* src = (z == 0) ? wq : (z == 1) ? wk : wv;
    float s = (z == 0) ? QSCALE : 1.0f;
    wbf[idx] = f2bf(src[idx & 65535] * s);
}

// ---------------- kernel 2: fused 1x1-conv projection -----------------------
__global__ __launch_bounds__(256) void proj_kernel(
    const float* __restrict__ xq, const float* __restrict__ xk, const float* __restrict__ xv,
    const float* __restrict__ bq, const float* __restrict__ bk, const float* __restrict__ bv,
    const unsigned short* __restrict__ wbf,
    unsigned short* __restrict__ Qo, unsigned short* __restrict__ Ko,
    unsigned short* __restrict__ VTo)
{
    __shared__ __align__(16) unsigned short alds[64 * 264];
    __shared__ __align__(16) unsigned char wlds[16384];
    const int z = blockIdx.y;
    const int b = blockIdx.x >> 6;
    const int n0 = (blockIdx.x & 63) << 6;
    const float* x    = (z == 0) ? xq : (z == 1) ? xk : xv;
    const float* bias = (z == 0) ? bq : (z == 1) ? bk : bv;
    const unsigned short* w = wbf + z * 65536;
    const int t = threadIdx.x;
    const int wv_ = t >> 6, l = t & 63, lr = l & 15, lg = l >> 4;

    #pragma unroll
    for (int it = 0; it < 16; ++it) {
        int idx = it * 256 + t;
        int c = idx >> 4, j4 = idx & 15;
        f32x4 v = *(const f32x4*)(x + (size_t)(b * CHD + c) * NTOK + n0 + j4 * 4);
        #pragma unroll
        for (int i = 0; i < 4; ++i)
            alds[(j4 * 4 + i) * 264 + c] = f2bf(v[i]);
    }
    __syncthreads();

    bf16x8 af[8];
    #pragma unroll
    for (int kk = 0; kk < 8; ++kk)
        af[kk] = *(const bf16x8*)&alds[(wv_ * 16 + lr) * 264 + kk * 32 + lg * 8];

    const float bsc = (z == 0) ? QSCALE : 1.0f;

    for (int dg = 0; dg < 8; ++dg) {
        __syncthreads();
        #pragma unroll
        for (int it = 0; it < 4; ++it) {
            int idx = it * 256 + t;
            int dr = idx >> 5, c16 = idx & 31;
            u32x4 vv = *(const u32x4*)(w + (size_t)(dg * 32 + dr) * CHD + c16 * 8);
            *(u32x4*)(wlds + ((dr * 512 + c16 * 16) ^ ((dr & 7) << 4))) = vv;
        }
        __syncthreads();
        #pragma unroll
        for (int dbi = 0; dbi < 2; ++dbi) {
            int dr = dbi * 16 + lr;
            int d = dg * 32 + dr;
            float bias_v = bias[d] * bsc;
            f32x4 acc = {bias_v, bias_v, bias_v, bias_v};
            #pragma unroll
            for (int kk = 0; kk < 8; ++kk) {
                bf16x8 bf = *(const bf16x8*)(wlds + ((dr * 512 + kk * 64 + lg * 16) ^ ((dr & 7) << 4)));
                acc = mfma16(af[kk], bf, acc);
            }
            if (z < 2) {
                unsigned short* o = (z == 0) ? Qo : Ko;
                #pragma unroll
                for (int r = 0; r < 4; ++r) {
                    int n = n0 + wv_ * 16 + lg * 4 + r;
                    o[(size_t)(b * NTOK + n) * CHD + d] = f2bf(acc[r]);
                }
            } else {
                int n = n0 + wv_ * 16 + lg * 4;
                u32x2 pk;
                pk[0] = (unsigned)f2bf(acc[0]) | ((unsigned)f2bf(acc[1]) << 16);
                pk[1] = (unsigned)f2bf(acc[2]) | ((unsigned)f2bf(acc[3]) << 16);
                *(u32x2*)(VTo + (size_t)(b * CHD + d) * NTOK + n) = pk;
            }
        }
    }
}

// ---------------- kernel 3: flash attention (KV-split x4, 256q/block) -------
// r15 = r11 revert (best proven: attn 97.5us, total 126.3us).
// 8-wave 512-thread blocks, 256 q-rows, grid 256 (1 block/CU, 2 waves/SIMD).
// amdgpu_waves_per_eu(2,2) pins 256 regs/wave (128 arch + 128 acc) — no spill.
// Swapped QK^T (S^T = mfma(K,Q)), pi-permuted K staging so post-softmax regs
// are the PV A-frag (cvt_pk only); defer-max THR=8; deferred per-lane l-sum;
// single barrier per iter: drain own lgkm+vmcnt, barrier, stage(kt+1)
// overlapping the whole iteration's compute.
// bid&7 -> (b, hf) XCD group; j=bid>>3: q2=j>>4, qtile=j&15, n0=qtile*256.
// LDS 64KB: buf c at c*32768: K 16KB (32 keys x 512B, pi-perm + swz
// ^((r&7)<<4)) | V 16KB (256 d-rows x 64B).
__global__ __attribute__((amdgpu_waves_per_eu(2, 2))) __launch_bounds__(512)
void attn_kernel(
    const unsigned short* __restrict__ Qp,
    const unsigned short* __restrict__ Kp,
    const unsigned short* __restrict__ VTp,
    unsigned short* __restrict__ Opart,      // (B,4,C,N) unnormalized bf16
    float* __restrict__ Mpart, float* __restrict__ Lpart)  // (B,4,N)
{
    __shared__ __align__(16) char smem[65536];
    const int bid = blockIdx.x;
    const int g = bid & 7, b = g >> 1, hf = g & 1;
    const int j = bid >> 3;
    const int q2 = j >> 4;
    const int n0 = (j & 15) * 256;
    const int part = hf * 2 + q2;
    const int kvbase = hf * 2048 + q2 * 1024;
    const int t = threadIdx.x;
    const int w = t >> 6, l = t & 63, lr = l & 15, lg = l >> 4;

    const char* Kby = (const char*)(Kp + (size_t)b * NTOK * CHD);
    const char* Vby = (const char*)(VTp + (size_t)b * CHD * NTOK);
    const unsigned short* Qb = Qp + (size_t)b * NTOK * CHD;

    // Q fragments: wave owns rows [n0 + w*32, +32)
    bf16x8 qf[2][8];
    #pragma unroll
    for (int nb = 0; nb < 2; ++nb)
        #pragma unroll
        for (int kk = 0; kk < 8; ++kk)
            qf[nb][kk] = *(const bf16x8*)(Qb + (size_t)(n0 + w * 32 + nb * 16 + lr) * CHD + kk * 32 + lg * 8);
    asm volatile("" ::: "memory");

    // staging: wave w stages bytes [w*2048, +2048) of each 16KB tile
    auto stage = [&](int bsel, int kt2) {
        const char* ks = Kby + (size_t)(kvbase + kt2 * KB) * 512;
        const char* vs = Vby + (size_t)(kvbase + kt2 * KB) * 2;
        char* kd = smem + bsel * 32768 + w * 2048;
        char* vd = smem + bsel * 32768 + 16384 + w * 2048;
        #pragma unroll
        for (int jj = 0; jj < 2; ++jj) {
            int p = w * 2048 + jj * 1024 + l * 16;
            int i = p >> 9, c = p & 511;
            int pi = ((i >> 2) & 3) * 8 + ((i >> 4) & 1) * 4 + (i & 3);  // row perm
            GLOAD(ks + pi * 512 + (c ^ ((i & 7) << 4)), kd + jj * 1024);
        }
        #pragma unroll
        for (int jj = 0; jj < 2; ++jj) {
            int p = w * 2048 + jj * 1024 + l * 16;
            GLOAD(vs + (p >> 6) * 8192 + (p & 63), vd + jj * 1024);  // V row d=p>>6
        }
    };

    stage(0, 0);                      // prologue: tile 0 into buf 0

    f32x4 o[2][16];
    #pragma unroll
    for (int nb = 0; nb < 2; ++nb)
        #pragma unroll
        for (int db = 0; db < 16; ++db)
            o[nb][db] = (f32x4){0.f, 0.f, 0.f, 0.f};
    float mrow[2] = {-1e30f, -1e30f};
    float lpart[2] = {0.f, 0.f};      // per-lane partial; summed at epilogue

    #pragma unroll 1
    for (int kt = 0; kt < NIT; ++kt) {
        const int cur = kt & 1;
        // drain own LDS reads (buf cur^1) and own stage of tile kt, then sync:
        // after this barrier, buf cur is fully resident for ALL waves and
        // buf cur^1 is reusable by ALL waves.
        asm volatile("s_waitcnt lgkmcnt(0) vmcnt(0)" ::: "memory");
        __builtin_amdgcn_s_barrier();
        __builtin_amdgcn_sched_barrier(0);
        if (kt + 1 < NIT) stage(cur ^ 1, kt + 1);     // overlap loads w/ compute

        const char* kB = smem + cur * 32768;
        const char* vB = kB + 16384;

        // ---- S^T = K Q^T : lane holds S[k=cb*16+lg*4+r][q=nb*16+lr] ----
        f32x4 s[2][2];
        #pragma unroll
        for (int nb = 0; nb < 2; ++nb)
            #pragma unroll
            for (int cb = 0; cb < 2; ++cb)
                s[nb][cb] = (f32x4){0.f, 0.f, 0.f, 0.f};
        __builtin_amdgcn_s_setprio(1);
        #pragma unroll
        for (int kk = 0; kk < 8; ++kk) {
            #pragma unroll
            for (int cb = 0; cb < 2; ++cb) {
                int row = cb * 16 + lr;
                bf16x8 kf = *(const bf16x8*)(kB + row * 512 + ((kk * 64 + lg * 16) ^ ((row & 7) << 4)));
                s[0][cb] = mfma16(kf, qf[0][kk], s[0][cb]);
                s[1][cb] = mfma16(kf, qf[1][kk], s[1][cb]);
            }
        }
        __builtin_amdgcn_s_setprio(0);

        // ---- online softmax, defer-max (THR=8), quad-uniform reduce ----
        float pm[2];
        #pragma unroll
        for (int nb = 0; nb < 2; ++nb) {
            float t8 = fmaxf(fmaxf(fmaxf(s[nb][0][0], s[nb][0][1]), fmaxf(s[nb][0][2], s[nb][0][3])),
                             fmaxf(fmaxf(s[nb][1][0], s[nb][1][1]), fmaxf(s[nb][1][2], s[nb][1][3])));
            pm[nb] = xmax32(t8);
        }
        bool grow = (pm[0] > mrow[0] + RESCALE_THR) || (pm[1] > mrow[1] + RESCALE_THR);
        if (__any((int)grow)) {
            #pragma unroll
            for (int nb = 0; nb < 2; ++nb) {
                float mn = fmaxf(mrow[nb], pm[nb]);
                float resc = __builtin_amdgcn_exp2f(mrow[nb] - mn);
                mrow[nb] = mn;
                lpart[nb] *= resc;
                f32x4 r4;                               // resc for q = lg*4 + r
                #pragma unroll
                for (int r = 0; r < 4; ++r)
                    r4[r] = __shfl(resc, lg * 4 + r);
                #pragma unroll
                for (int db = 0; db < 16; ++db)
                    o[nb][db] *= r4;
            }
        }
        bf16x8 pb[2];
        #pragma unroll
        for (int nb = 0; nb < 2; ++nb) {
            float ps = 0.f;
            #pragma unroll
            for (int cb = 0; cb < 2; ++cb)
                #pragma unroll
                for (int r = 0; r < 4; ++r) {
                    float p = __builtin_amdgcn_exp2f(s[nb][cb][r] - mrow[nb]);
                    s[nb][cb][r] = p;
                    ps += p;
                }
            lpart[nb] += ps;                            // per-lane partial only
            // registers -> PV A-frag (k order matches the staged pi-permutation)
            u32x4 pw;
            pw[0] = cvtpk(s[nb][0][0], s[nb][0][1]);
            pw[1] = cvtpk(s[nb][0][2], s[nb][0][3]);
            pw[2] = cvtpk(s[nb][1][0], s[nb][1][1]);
            pw[3] = cvtpk(s[nb][1][2], s[nb][1][3]);
            pb[nb] = __builtin_bit_cast(bf16x8, pw);
        }

        // ---- O += P V ----
        __builtin_amdgcn_s_setprio(1);
        #pragma unroll
        for (int db = 0; db < 16; ++db) {
            bf16x8 vf = *(const bf16x8*)(vB + (db * 16 + lr) * 64 + lg * 16);
            o[0][db] = mfma16(pb[0], vf, o[0][db]);
            o[1][db] = mfma16(pb[1], vf, o[1][db]);
        }
        __builtin_amdgcn_s_setprio(0);
    }

    // ---- epilogue: one cross-lane l-sum, then write the 32-row partial ----
    float lrow[2];
    #pragma unroll
    for (int nb = 0; nb < 2; ++nb)
        lrow[nb] = xsum32(lpart[nb]);

    unsigned short* Ob = Opart + (size_t)(b * 4 + part) * CHD * NTOK;
    #pragma unroll
    for (int nb = 0; nb < 2; ++nb)
        #pragma unroll
        for (int db = 0; db < 16; ++db) {
            int d = db * 16 + lr;
            int n = n0 + w * 32 + nb * 16 + lg * 4;
            u32x2 pk;
            pk[0] = (unsigned)f2bf(o[nb][db][0]) | ((unsigned)f2bf(o[nb][db][1]) << 16);
            pk[1] = (unsigned)f2bf(o[nb][db][2]) | ((unsigned)f2bf(o[nb][db][3]) << 16);
            *(u32x2*)(Ob + (size_t)d * NTOK + n) = pk;
        }
    if (lg == 0) {    // lanes 0..15 hold m/l for q = lr
        #pragma unroll
        for (int nb = 0; nb < 2; ++nb) {
            int n = n0 + w * 32 + nb * 16 + lr;
            Mpart[(size_t)(b * 4 + part) * NTOK + n] = mrow[nb];
            Lpart[(size_t)(b * 4 + part) * NTOK + n] = lrow[nb];
        }
    }
}

// ---------------- kernel 4: merge the four KV-quarter partials --------------
__global__ __launch_bounds__(256) void merge_kernel(
    const unsigned short* __restrict__ Opart,
    const float* __restrict__ Mpart, const float* __restrict__ Lpart,
    float* __restrict__ out)
{
    int tid = blockIdx.x * 256 + threadIdx.x;
    int n = (tid & 1023) * 4;
    int c = (tid >> 10) & 255;
    int b = tid >> 18;
    u32x2 ov[4]; f32x4 mv[4], lv[4];
    #pragma unroll
    for (int p = 0; p < 4; ++p) {
        ov[p] = *(const u32x2*)(Opart + (size_t)(b * 4 + p) * CHD * NTOK + (size_t)c * NTOK + n);
        mv[p] = *(const f32x4*)(Mpart + (size_t)(b * 4 + p) * NTOK + n);
        lv[p] = *(const f32x4*)(Lpart + (size_t)(b * 4 + p) * NTOK + n);
    }
    f32x4 res;
    #pragma unroll
    for (int r = 0; r < 4; ++r) {
        float mm = fmaxf(fmaxf(mv[0][r], mv[1][r]), fmaxf(mv[2][r], mv[3][r]));
        float num = 0.f, den = 0.f;
        #pragma unroll
        for (int p = 0; p < 4; ++p) {
            float sc = __builtin_amdgcn_exp2f(mv[p][r] - mm);
            num += bf2f((unsigned short)(ov[p][r >> 1] >> ((r & 1) * 16))) * sc;
            den += lv[p][r] * sc;
        }
        res[r] = num / den;
    }
    *(f32x4*)(out + (size_t)b * CHD * NTOK + (size_t)c * NTOK + n) = res;
}

// ---------------------------------------------------------------------------
extern "C" void kernel_launch(void* const* d_in, const int* in_sizes, int n_in,
                              void* d_out, int out_size, void* d_ws, size_t ws_size,
                              hipStream_t stream) {
    const float* xq = (const float*)d_in[0];
    const float* xk = (const float*)d_in[1];
    const float* xv = (const float*)d_in[2];
    const float* wq = (const float*)d_in[3];
    const float* bq = (const float*)d_in[4];
    const float* wk = (const float*)d_in[5];
    const float* bk = (const float*)d_in[6];
    const float* wv = (const float*)d_in[7];
    const float* bv = (const float*)d_in[8];

    char* ws = (char*)d_ws;
    unsigned short* wbf = (unsigned short*)ws;                       // 384 KB
    unsigned short* Qp  = (unsigned short*)(ws + 393216);            // 8 MB
    unsigned short* Kp  = (unsigned short*)(ws + 8781824);           // 8 MB
    unsigned short* VTp = (unsigned short*)(ws + 17170432);          // 8 MB
    unsigned short* Op  = (unsigned short*)(ws + 25559040);          // 32 MB
    float* Mp = (float*)(ws + 59113472);                             // 256 KB
    float* Lp = (float*)(ws + 59375616);                             // 256 KB

    hipLaunchKernelGGL(wconv_kernel, dim3(768), dim3(256), 0, stream, wq, wk, wv, wbf);
    hipLaunchKernelGGL(proj_kernel, dim3(256, 3), dim3(256), 0, stream,
                       xq, xk, xv, bq, bk, bv, wbf, Qp, Kp, VTp);
    hipLaunchKernelGGL(attn_kernel, dim3(256), dim3(512), 0, stream, Qp, Kp, VTp, Op, Mp, Lp);
    hipLaunchKernelGGL(merge_kernel, dim3(4096), dim3(256), 0, stream, Op, Mp, Lp, (float*)d_out);
}